// Round 6
// baseline (168.697 us; speedup 1.0000x reference)
//
#include <hip/hip_runtime.h>

// Problem constants (from reference config)
#define FD 56          // depth samples: linspace(2, 58, 56)
#define FH 112         // 900 / 8
#define FW 200         // 1600 / 8
#define VD 16          // volume D
#define VH 200         // volume H
#define VW 200         // volume W
#define NC 32          // channels
#define NPIX (FH * FW)         // 22400 = 350 * 64 exactly
#define CSTRIDE (VD * VH * VW) // 640000 floats per channel

typedef float f2v __attribute__((ext_vector_type(2)));
typedef f2v uf2v __attribute__((aligned(4)));   // 8B vector load, 4B-align safe

__global__ __launch_bounds__(256)
void VolumeTransform_3667902071054_kernel(const float* __restrict__ vol,
                                          const float* __restrict__ Km,
                                          const float* __restrict__ Tm,
                                          float* __restrict__ out) {
    // ---- fused projection matrix M = e2f @ T @ [[K^-1,0],[0,1]] ----
    __shared__ float sM[12];
    if (threadIdx.x == 0) {
        float a = Km[0], b = Km[1], c = Km[2];
        float d = Km[3], e = Km[4], f = Km[5];
        float g = Km[6], h = Km[7], i = Km[8];
        float A00 = e * i - f * h, A01 = c * h - b * i, A02 = b * f - c * e;
        float A10 = f * g - d * i, A11 = a * i - c * g, A12 = c * d - a * f;
        float A20 = d * h - e * g, A21 = b * g - a * h, A22 = a * e - b * d;
        float det = a * A00 + b * A10 + c * A20;
        float r = 1.0f / det;
        float Ki[9] = {A00 * r, A01 * r, A02 * r,
                       A10 * r, A11 * r, A12 * r,
                       A20 * r, A21 * r, A22 * r};
        float R[4][4];
        for (int rr = 0; rr < 4; ++rr) {
            for (int cc = 0; cc < 3; ++cc)
                R[rr][cc] = Tm[rr * 4 + 0] * Ki[0 * 3 + cc]
                          + Tm[rr * 4 + 1] * Ki[1 * 3 + cc]
                          + Tm[rr * 4 + 2] * Ki[2 * 3 + cc];
            R[rr][3] = Tm[rr * 4 + 3];
        }
        const float s[3] = {2.5f, 2.5f, 2.5f};
        const float t[3] = {100.0f, 100.0f, 2.5f};
        for (int rr = 0; rr < 3; ++rr)
            for (int cc = 0; cc < 4; ++cc)
                sM[rr * 4 + cc] = s[rr] * R[rr][cc] + t[rr] * R[3][cc];
    }
    __syncthreads();

    // 1400 blocks = 4 channel-pair-groups (fast) x 350 pixel-groups.
    const int cg   = blockIdx.x & 3;      // 0..3
    const int pg   = blockIdx.x >> 2;     // 0..349
    const int lane = threadIdx.x & 63;
    const int wv   = threadIdx.x >> 6;
    const int c0   = (cg * 4 + wv) * 2;   // 0,2,..,30
    const int p    = pg * 64 + lane;      // 0..22399
    const int py   = p / FW;
    const int px   = p - py * FW;

    const float gx = (float)px * (1599.0f / 199.0f);
    const float gy = (float)py * (899.0f / 111.0f);

    const float m03 = sM[3], m13 = sM[7], m23 = sM[11];
    const float ax = sM[0] * gx + sM[1] * gy + sM[2];
    const float ay = sM[4] * gx + sM[5] * gy + sM[6];
    const float az = sM[8] * gx + sM[9] * gy + sM[10];

    // ---- closed-form hit interval: coords affine in gd => hit set is one
    //      gd-interval. Compute it, widen by 1 step for fp safety (loop body
    //      is mask-protected and index-clamped, so inclusion is harmless). ----
    float dlo = 2.0f, dhi = 58.0f;
    {
        // need lo < a*gd + b < hi for each axis
        const float A[3]  = {ax, ay, az};
        const float Bv[3] = {m03, m13, m23};
        const float HI[3] = {(float)VW, (float)VH, (float)VD};
        for (int q = 0; q < 3; ++q) {
            float a = A[q], b = Bv[q], hi = HI[q];
            if (a > 0.0f)      { dlo = fmaxf(dlo, (-1.0f - b) / a); dhi = fminf(dhi, (hi - b) / a); }
            else if (a < 0.0f) { dlo = fmaxf(dlo, (hi - b) / a);    dhi = fminf(dhi, (-1.0f - b) / a); }
            else if (!(b > -1.0f && b < hi)) { dlo = 1e30f; dhi = -1e30f; }
        }
    }
    int klo = (int)ceilf((dlo - 2.0f) * (55.0f / 56.0f));
    int khi = (int)floorf((dhi - 2.0f) * (55.0f / 56.0f));
    klo = max(klo - 1, 0);
    khi = min(khi + 1, FD - 1);

    const float* __restrict__ volc0 = vol + (size_t)c0 * CSTRIDE;
    const float* __restrict__ volc1 = volc0 + CSTRIDE;
    float acc0 = 0.0f, acc1 = 0.0f;

    // ---- branch-free inner loop over exact hit interval ----
#pragma unroll 2
    for (int k = klo; k <= khi; ++k) {
        const float gd = 2.0f + (float)k * (56.0f / 55.0f);
        const float fx = fmaf(ax, gd, m03);
        const float fy = fmaf(ay, gd, m13);
        const float fz = fmaf(az, gd, m23);

        const bool valid = (fx > -1.0f) && (fx < (float)VW) &&
                           (fy > -1.0f) && (fy < (float)VH) &&
                           (fz > -1.0f) && (fz < (float)VD);
        const float vm = valid ? 1.0f : 0.0f;

        const float xf = floorf(fx), yf = floorf(fy), zf = floorf(fz);
        const float tx = fx - xf, ty = fy - yf, tz = fz - zf;
        const int ix = (int)xf, iy = (int)yf, iz = (int)zf;

        // x handled as an always-8B load at clamped xi0; remap weights:
        //  interior: (1-tx, tx); ix==-1: (tx, 0); ix==VW-1: (0, 1-tx)
        float wlo = (ix >= 0) ? (1.0f - tx) : tx;
        wlo = (ix >= VW - 1) ? 0.0f : wlo;
        float whi = (ix >= 0) ? tx : 0.0f;
        whi = (ix >= VW - 1) ? (1.0f - tx) : whi;

        const float wy0 = (iy >= 0)     ? (1.0f - ty) : 0.0f;
        const float wy1 = (iy < VH - 1) ? ty          : 0.0f;
        const float wz0 = ((iz >= 0)     ? (1.0f - tz) : 0.0f) * vm;
        const float wz1 = ((iz < VD - 1) ? tz          : 0.0f) * vm;
        const float w00 = wz0 * wy0, w01 = wz0 * wy1;
        const float w10 = wz1 * wy0, w11 = wz1 * wy1;

        const int xi0 = min(max(ix, 0), VW - 2);
        const int yo0 = min(max(iy,     0), VH - 1) * VW;
        const int yo1 = min(max(iy + 1, 0), VH - 1) * VW;
        const int zo0 = min(max(iz,     0), VD - 1) * (VH * VW);
        const int zo1 = min(max(iz + 1, 0), VD - 1) * (VH * VW);

        const int o00 = zo0 + yo0 + xi0, o01 = zo0 + yo1 + xi0;
        const int o10 = zo1 + yo0 + xi0, o11 = zo1 + yo1 + xi0;

        const f2v a00 = *(const uf2v*)(volc0 + o00);
        const f2v a01 = *(const uf2v*)(volc0 + o01);
        const f2v a10 = *(const uf2v*)(volc0 + o10);
        const f2v a11 = *(const uf2v*)(volc0 + o11);
        const f2v b00 = *(const uf2v*)(volc1 + o00);
        const f2v b01 = *(const uf2v*)(volc1 + o01);
        const f2v b10 = *(const uf2v*)(volc1 + o10);
        const f2v b11 = *(const uf2v*)(volc1 + o11);

        const float h00a = wlo * a00.x + whi * a00.y;
        const float h01a = wlo * a01.x + whi * a01.y;
        const float h10a = wlo * a10.x + whi * a10.y;
        const float h11a = wlo * a11.x + whi * a11.y;
        const float h00b = wlo * b00.x + whi * b00.y;
        const float h01b = wlo * b01.x + whi * b01.y;
        const float h10b = wlo * b10.x + whi * b10.y;
        const float h11b = wlo * b11.x + whi * b11.y;

        acc0 += w00 * h00a + w01 * h01a + w10 * h10a + w11 * h11a;
        acc1 += w00 * h00b + w01 * h01b + w10 * h10b + w11 * h11b;
    }

    out[c0 * NPIX + p]       = acc0;
    out[(c0 + 1) * NPIX + p] = acc1;
}

extern "C" void kernel_launch(void* const* d_in, const int* in_sizes, int n_in,
                              void* d_out, int out_size, void* d_ws, size_t ws_size,
                              hipStream_t stream) {
    (void)in_sizes; (void)n_in; (void)out_size; (void)d_ws; (void)ws_size;
    const float* vol = (const float*)d_in[0]; // (1,32,16,200,200) fp32
    const float* Km  = (const float*)d_in[1]; // (1,3,3) fp32
    const float* Tm  = (const float*)d_in[2]; // (1,4,4) fp32
    float* out = (float*)d_out;               // (1,32,112,200) fp32

    VolumeTransform_3667902071054_kernel<<<dim3(1400), dim3(256), 0, stream>>>(vol, Km, Tm, out);
}